// Round 8
// baseline (249.831 us; speedup 1.0000x reference)
//
#include <hip/hip_runtime.h>

// B=8, N=M=4096, D=3, fp32 in/out.
constexpr int B = 8;
constexpr int N = 4096;           // == M
constexpr int PTS = B * N;        // 32768 points per cloud

#define TPB 256                   // threads per block
#define R 16                      // own points per thread -> TPB*R = 4096 = N
#define RP (R / 2)                // packed float2 pairs per thread
#define CHUNK 64                  // other points staged per block (1 KB LDS)
#define KC (N / CHUNK)            // 64 chunks = blocks per (dir,b) group
#define NGRP (2 * B)              // 16 groups

typedef float float2v __attribute__((ext_vector_type(2)));

// Single-launch fused chamfer, atomic-free per-point combine.
// Block = (chunk, dir, batch). Body: Gram-form min over one CHUNK for all N
// own points (v_pk_fma_f32 + min3), PLAIN coalesced stores of per-chunk
// partial mins into partials[g][chunk][N].
// Tail: per-(dir,b) poisoned done-counter; the LAST block of each group
// min-reduces its group's KC partial rows with pipelined float4 loads
// (release fence before gcount RMW on producers; acquire fence after on the
// consumer -> cross-XCD visible per the gfx950 memory model), then sqrt+sum,
// then a global poisoned done-counter picks the final 16-way summer.
__global__ __launch_bounds__(TPB) void chamfer_fused3(
        const float* __restrict__ x1, const float* __restrict__ y1,
        float* __restrict__ partials,         // [NGRP][KC][N]  (16 MB)
        unsigned int* __restrict__ gcount,    // [NGRP] poisoned 0xAAAAAAAA
        float* __restrict__ gsum,             // [NGRP] written before read
        unsigned int* __restrict__ done,      // [1]    poisoned
        float* __restrict__ out, float scale) {
    __shared__ float4 qs[CHUNK];

    const int chunk = blockIdx.x;
    const int dir   = blockIdx.y;
    const int b     = blockIdx.z;
    const int g     = dir * B + b;

    const float* own = dir ? y1 : x1;
    const float* oth = dir ? x1 : y1;

    // Stage CHUNK other-points as float4(qx,qy,qz,|q|^2).
    if (threadIdx.x < CHUNK) {
        const float* op = oth + ((size_t)b * N + chunk * CHUNK + threadIdx.x) * 3;
        float qx = op[0], qy = op[1], qz = op[2];
        qs[threadIdx.x] = make_float4(qx, qy, qz, fmaf(qx, qx, fmaf(qy, qy, qz * qz)));
    }

    // R own points per thread, strided by TPB; coefficients packed in pairs.
    float2v mx2[RP], my2[RP], mz2[RP], acc2[RP];
    float xx[R];
    #pragma unroll
    for (int p = 0; p < RP; p++) {
        #pragma unroll
        for (int e = 0; e < 2; e++) {
            const int r = 2 * p + e;
            const float* pp = own + ((size_t)b * N + threadIdx.x + r * TPB) * 3;
            float px = pp[0], py = pp[1], pz = pp[2];
            mx2[p][e] = -2.0f * px;
            my2[p][e] = -2.0f * py;
            mz2[p][e] = -2.0f * pz;
            xx[r] = fmaf(px, px, fmaf(py, py, pz * pz));
        }
        acc2[p] = float2v{3.4e38f, 3.4e38f};
    }

    __syncthreads();

    #pragma unroll 2
    for (int j = 0; j < CHUNK; j += 2) {
        union { float4 f4; float2v f2[2]; } qa0, qa1;
        qa0.f4 = qs[j];                // ds_read_b128, broadcast (no conflicts)
        qa1.f4 = qs[j + 1];
        float2v xy0 = qa0.f2[0], zw0 = qa0.f2[1];
        float2v xy1 = qa1.f2[0], zw1 = qa1.f2[1];
        #pragma unroll
        for (int p = 0; p < RP; p++) {
            float2v g0, g1;
            asm("v_pk_fma_f32 %0, %1, %2, %1 op_sel:[0,0,1] op_sel_hi:[0,1,1]"
                : "=v"(g0) : "v"(zw0), "v"(mz2[p]));
            asm("v_pk_fma_f32 %0, %1, %2, %1 op_sel:[0,0,1] op_sel_hi:[0,1,1]"
                : "=v"(g1) : "v"(zw1), "v"(mz2[p]));
            asm("v_pk_fma_f32 %0, %1, %2, %3 op_sel:[1,0,0] op_sel_hi:[1,1,1]"
                : "=v"(g0) : "v"(xy0), "v"(my2[p]), "v"(g0));
            asm("v_pk_fma_f32 %0, %1, %2, %3 op_sel:[1,0,0] op_sel_hi:[1,1,1]"
                : "=v"(g1) : "v"(xy1), "v"(my2[p]), "v"(g1));
            asm("v_pk_fma_f32 %0, %1, %2, %3 op_sel:[0,0,0] op_sel_hi:[0,1,1]"
                : "=v"(g0) : "v"(xy0), "v"(mx2[p]), "v"(g0));
            asm("v_pk_fma_f32 %0, %1, %2, %3 op_sel:[0,0,0] op_sel_hi:[0,1,1]"
                : "=v"(g1) : "v"(xy1), "v"(mx2[p]), "v"(g1));
            acc2[p].x = fminf(fminf(acc2[p].x, g0.x), g1.x);
            acc2[p].y = fminf(fminf(acc2[p].y, g0.y), g1.y);
        }
    }

    // Plain coalesced stores of this chunk's partial mins (no contention).
    float* dst = partials + ((size_t)g * KC + chunk) * N;
    #pragma unroll
    for (int p = 0; p < RP; p++) {
        dst[threadIdx.x + (2 * p) * TPB]     = fmaxf(acc2[p].x + xx[2 * p], 0.0f);
        dst[threadIdx.x + (2 * p + 1) * TPB] = fmaxf(acc2[p].y + xx[2 * p + 1], 0.0f);
    }

    // Group done-counter (release: fence makes partial stores agent-visible
    // before the RMW).
    __threadfence();
    __syncthreads();
    __shared__ bool amLast;
    if (threadIdx.x == 0) {
        unsigned int old = atomicAdd(&gcount[g], 1u);
        amLast = (old == 0xAAAAAAAAu + (unsigned)(KC - 1));
    }
    __syncthreads();
    if (!amLast) return;

    // Acquire: invalidate stale cache lines, then min-reduce the group's KC
    // partial rows with vectorized, pipelined loads.
    __threadfence();
    const float* gp = partials + (size_t)g * KC * N;
    const int base = threadIdx.x * 16;        // 16 consecutive points/thread
    float4 m[4];
    #pragma unroll
    for (int k = 0; k < 4; k++)
        m[k] = *(const float4*)(gp + base + 4 * k);
    #pragma unroll 4
    for (int c = 1; c < KC; c++) {
        #pragma unroll
        for (int k = 0; k < 4; k++) {
            float4 v = *(const float4*)(gp + (size_t)c * N + base + 4 * k);
            m[k].x = fminf(m[k].x, v.x);
            m[k].y = fminf(m[k].y, v.y);
            m[k].z = fminf(m[k].z, v.z);
            m[k].w = fminf(m[k].w, v.w);
        }
    }

    float s = 0.0f;
    #pragma unroll
    for (int k = 0; k < 4; k++) {
        s += sqrtf(1e-8f + m[k].x);
        s += sqrtf(1e-8f + m[k].y);
        s += sqrtf(1e-8f + m[k].z);
        s += sqrtf(1e-8f + m[k].w);
    }

    #pragma unroll
    for (int off = 32; off > 0; off >>= 1) s += __shfl_down(s, off, 64);
    __shared__ float part[4];
    const int wid = threadIdx.x >> 6, lane = threadIdx.x & 63;
    if (lane == 0) part[wid] = s;
    __syncthreads();

    if (threadIdx.x == 0) {
        float sg = part[0] + part[1] + part[2] + part[3];
        __hip_atomic_store(&gsum[g], sg, __ATOMIC_RELEASE,
                           __HIP_MEMORY_SCOPE_AGENT);
        unsigned int o2 = __hip_atomic_fetch_add(done, 1u, __ATOMIC_ACQ_REL,
                                                 __HIP_MEMORY_SCOPE_AGENT);
        if (o2 == 0xAAAAAAAAu + (unsigned)(NGRP - 1)) {
            __threadfence();
            float t = 0.0f;
            #pragma unroll
            for (int k = 0; k < NGRP; k++)
                t += __hip_atomic_load(&gsum[k], __ATOMIC_RELAXED,
                                       __HIP_MEMORY_SCOPE_AGENT);
            out[0] = t * scale;
        }
    }
}

extern "C" void kernel_launch(void* const* d_in, const int* in_sizes, int n_in,
                              void* d_out, int out_size, void* d_ws, size_t ws_size,
                              hipStream_t stream) {
    const float* x1 = (const float*)d_in[0];   // (B, N, 3)
    const float* y1 = (const float*)d_in[1];   // (B, N, 3)
    float* out = (float*)d_out;

    float*        partials = (float*)d_ws;                    // 16 MB
    unsigned int* gcount   = (unsigned int*)(partials + (size_t)NGRP * KC * N);
    float*        gsum     = (float*)(gcount + NGRP);
    unsigned int* done     = (unsigned int*)(gsum + NGRP);

    dim3 grid(KC, 2, B);                       // 64 x 2 x 8 = 1024 blocks
    chamfer_fused3<<<grid, TPB, 0, stream>>>(x1, y1, partials, gcount, gsum,
                                             done, out, 1.0f / (B * N));
}

// Round 9
// 92.116 us; speedup vs baseline: 2.7121x; 2.7121x over previous
//
#include <hip/hip_runtime.h>

// B=8, N=M=4096, D=3, fp32 in/out.
constexpr int B = 8;
constexpr int N = 4096;           // == M
constexpr int PTS = B * N;        // 32768 points per cloud
constexpr int TOT = 2 * PTS;      // 65536 (both directions)

#define TPB 256                   // threads per block
#define R 16                      // own points per thread -> TPB*R = 4096 = N
#define RP (R / 2)                // packed float2 pairs per thread
#define JR 64                     // other-points (j) per block
#define KJ (N / JR)               // 64 j-ranges per (dir,b) group

typedef float float2v __attribute__((ext_vector_type(2)));

// Phase 0: qpre[dir][p] = float4(qx,qy,qz,|q|^2); dir0 from y1, dir1 from x1.
// Thread 0 zeroes d_out (poisoned 0xAA; finish accumulates with atomicAdd).
__global__ __launch_bounds__(256) void prep(
        const float* __restrict__ x1, const float* __restrict__ y1,
        float4* __restrict__ qpre, float* __restrict__ out) {
    int tid = blockIdx.x * 256 + threadIdx.x;
    if (tid == 0) out[0] = 0.0f;
    if (tid >= TOT) return;
    int dir = tid >> 15;
    int p   = tid & (PTS - 1);
    const float* src = dir ? x1 : y1;
    float qx = src[3 * p], qy = src[3 * p + 1], qz = src[3 * p + 2];
    qpre[tid] = make_float4(qx, qy, qz, fmaf(qx, qx, fmaf(qy, qy, qz * qz)));
}

// Phase 1: block = (jrange, dir, batch). Each block holds ALL N own points
// (256 thr x R=16) and min-reduces over JR=64 other points via the Gram form
//   g = |q|^2 - 2 p.q   (+|p|^2, clamp >= 0 in the epilogue store).
// q comes from qpre with a WAVE-UNIFORM address (uniform induction var +
// __restrict__ const pointer) -> compiler scalarizes to s_load (scalar pipe,
// parallel to VALU). No LDS, no __syncthreads, no atomics.
// Math: v_pk_fma_f32 (2 fp32 FMA/instr) via asm, z->y->x order (bit-exact
// with prior rounds), 2-j min3 fold.
__global__ __launch_bounds__(TPB) void chamfer_main(
        const float* __restrict__ x1, const float* __restrict__ y1,
        const float4* __restrict__ qpre,
        float* __restrict__ partials) {       // [KJ][TOT]
    const int jrange = blockIdx.x;
    const int dir    = blockIdx.y;
    const int b      = blockIdx.z;

    const float* own = dir ? y1 : x1;

    // R own points per thread, strided by TPB; coefficients packed in pairs.
    float2v mx2[RP], my2[RP], mz2[RP], acc2[RP];
    float xx[R];
    #pragma unroll
    for (int p = 0; p < RP; p++) {
        #pragma unroll
        for (int e = 0; e < 2; e++) {
            const int r = 2 * p + e;
            const float* pp = own + ((size_t)b * N + threadIdx.x + r * TPB) * 3;
            float px = pp[0], py = pp[1], pz = pp[2];
            mx2[p][e] = -2.0f * px;
            my2[p][e] = -2.0f * py;
            mz2[p][e] = -2.0f * pz;
            xx[r] = fmaf(px, px, fmaf(py, py, pz * pz));
        }
        acc2[p] = float2v{3.4e38f, 3.4e38f};
    }

    // Uniform q pointer for this block's j-range.
    const float4* __restrict__ qp =
        qpre + (size_t)dir * PTS + (size_t)b * N + (size_t)jrange * JR;

    #pragma unroll 8
    for (int t = 0; t < JR / 2; t++) {
        float4 qv0 = qp[2 * t];        // wave-uniform -> s_load
        float4 qv1 = qp[2 * t + 1];
        float2v xy0 = {qv0.x, qv0.y}, zw0 = {qv0.z, qv0.w};
        float2v xy1 = {qv1.x, qv1.y}, zw1 = {qv1.z, qv1.w};
        #pragma unroll
        for (int p = 0; p < RP; p++) {
            float2v g0, g1;
            // g = q.z * mz + q.w   (q.z, q.w broadcast to both halves)
            asm("v_pk_fma_f32 %0, %1, %2, %1 op_sel:[0,0,1] op_sel_hi:[0,1,1]"
                : "=v"(g0) : "v"(zw0), "v"(mz2[p]));
            asm("v_pk_fma_f32 %0, %1, %2, %1 op_sel:[0,0,1] op_sel_hi:[0,1,1]"
                : "=v"(g1) : "v"(zw1), "v"(mz2[p]));
            // g = q.y * my + g     (q.y = hi half, broadcast)
            asm("v_pk_fma_f32 %0, %1, %2, %3 op_sel:[1,0,0] op_sel_hi:[1,1,1]"
                : "=v"(g0) : "v"(xy0), "v"(my2[p]), "v"(g0));
            asm("v_pk_fma_f32 %0, %1, %2, %3 op_sel:[1,0,0] op_sel_hi:[1,1,1]"
                : "=v"(g1) : "v"(xy1), "v"(my2[p]), "v"(g1));
            // g = q.x * mx + g     (q.x = lo half, broadcast)
            asm("v_pk_fma_f32 %0, %1, %2, %3 op_sel:[0,0,0] op_sel_hi:[0,1,1]"
                : "=v"(g0) : "v"(xy0), "v"(mx2[p]), "v"(g0));
            asm("v_pk_fma_f32 %0, %1, %2, %3 op_sel:[0,0,0] op_sel_hi:[0,1,1]"
                : "=v"(g1) : "v"(xy1), "v"(mx2[p]), "v"(g1));
            // 2-j fold -> v_min3_f32 per half.
            acc2[p].x = fminf(fminf(acc2[p].x, g0.x), g1.x);
            acc2[p].y = fminf(fminf(acc2[p].y, g0.y), g1.y);
        }
    }

    // Coalesced partial stores (kernel-boundary coherence; no atomics).
    float* dst = partials + (size_t)jrange * TOT + (size_t)dir * PTS + (size_t)b * N;
    #pragma unroll
    for (int p = 0; p < RP; p++) {
        dst[threadIdx.x + (2 * p) * TPB]     = fmaxf(acc2[p].x + xx[2 * p], 0.0f);
        dst[threadIdx.x + (2 * p + 1) * TPB] = fmaxf(acc2[p].y + xx[2 * p + 1], 0.0f);
    }
}

// Phase 2: per point min over KJ partial rows; sqrt; block-sum; one
// atomicAdd per block into the prep-zeroed scalar output.
__global__ __launch_bounds__(256) void chamfer_finish(
        const float* __restrict__ partials, float* __restrict__ out, float scale) {
    int p = blockIdx.x * 256 + threadIdx.x;   // [0, TOT)
    float m = partials[p];
    #pragma unroll
    for (int c = 1; c < KJ; c++) m = fminf(m, partials[(size_t)c * TOT + p]);
    float s = sqrtf(1e-8f + m) * scale;

    #pragma unroll
    for (int off = 32; off > 0; off >>= 1) s += __shfl_down(s, off, 64);

    __shared__ float part[4];
    const int wid = threadIdx.x >> 6, lane = threadIdx.x & 63;
    if (lane == 0) part[wid] = s;
    __syncthreads();
    if (threadIdx.x == 0) {
        atomicAdd(out, part[0] + part[1] + part[2] + part[3]);
    }
}

extern "C" void kernel_launch(void* const* d_in, const int* in_sizes, int n_in,
                              void* d_out, int out_size, void* d_ws, size_t ws_size,
                              hipStream_t stream) {
    const float* x1 = (const float*)d_in[0];   // (B, N, 3)
    const float* y1 = (const float*)d_in[1];   // (B, N, 3)
    float* out = (float*)d_out;

    float4* qpre    = (float4*)d_ws;                 // TOT float4 = 1 MB
    float* partials = (float*)(qpre + TOT);          // KJ * TOT = 16 MB

    prep<<<TOT / 256, 256, 0, stream>>>(x1, y1, qpre, out);

    dim3 grid(KJ, 2, B);                             // 64 x 2 x 8 = 1024 blocks
    chamfer_main<<<grid, TPB, 0, stream>>>(x1, y1, qpre, partials);

    chamfer_finish<<<TOT / 256, 256, 0, stream>>>(partials, out, 1.0f / (B * N));
}

// Round 10
// 89.136 us; speedup vs baseline: 2.8028x; 1.0334x over previous
//
#include <hip/hip_runtime.h>

// B=8, N=M=4096, D=3, fp32 in/out.
constexpr int B = 8;
constexpr int N = 4096;           // == M
constexpr int PTS = B * N;        // 32768 points per cloud
constexpr int TOT = 2 * PTS;      // 65536 (both directions)

#define TPB 256                   // threads per block
#define R 16                      // own points per thread -> TPB*R = 4096 = N
#define RP (R / 2)                // packed float2 pairs per thread
#define CHUNK 64                  // other points staged per block (1 KB LDS)
#define KC (N / CHUNK)            // 64 chunks = blocks per (dir,b) group

typedef float float2v __attribute__((ext_vector_type(2)));

// Phase 1: block = (chunk, dir, batch); grid 1024 blocks = 4 blocks/CU.
// Each block holds ALL N own points (256 thr x R=16) and min-reduces over one
// CHUNK=64 of other points via the Gram form g = |q|^2 - 2 p.q (+|p|^2,
// clamp >= 0 in the epilogue store).
// __launch_bounds__(256, 4): VGPR cap 128 -> coefficient arrays (~100 regs)
// stay RESIDENT (no scratch spill), 4 waves/EU.
// LDS q-pairs are manually double-buffered in registers so each ds_read_b128
// issues a full iteration ahead of its use.
__global__ __launch_bounds__(TPB, 4) void chamfer_main(
        const float* __restrict__ x1, const float* __restrict__ y1,
        float* __restrict__ partials,       // [KC][TOT]
        float* __restrict__ out) {
    __shared__ float4 qs[CHUNK];

    // Zero the output scalar (poisoned 0xAA; finish accumulates atomically).
    if (blockIdx.x == 0 && blockIdx.y == 0 && blockIdx.z == 0 && threadIdx.x == 0)
        out[0] = 0.0f;

    const int chunk = blockIdx.x;
    const int dir   = blockIdx.y;
    const int b     = blockIdx.z;

    const float* own = dir ? y1 : x1;
    const float* oth = dir ? x1 : y1;

    // Stage CHUNK other-points as float4(qx,qy,qz,|q|^2).
    if (threadIdx.x < CHUNK) {
        const float* op = oth + ((size_t)b * N + chunk * CHUNK + threadIdx.x) * 3;
        float qx = op[0], qy = op[1], qz = op[2];
        qs[threadIdx.x] = make_float4(qx, qy, qz, fmaf(qx, qx, fmaf(qy, qy, qz * qz)));
    }

    // R own points per thread, strided by TPB; coefficients packed in pairs.
    float2v mx2[RP], my2[RP], mz2[RP], acc2[RP];
    float xx[R];
    #pragma unroll
    for (int p = 0; p < RP; p++) {
        #pragma unroll
        for (int e = 0; e < 2; e++) {
            const int r = 2 * p + e;
            const float* pp = own + ((size_t)b * N + threadIdx.x + r * TPB) * 3;
            float px = pp[0], py = pp[1], pz = pp[2];
            mx2[p][e] = -2.0f * px;
            my2[p][e] = -2.0f * py;
            mz2[p][e] = -2.0f * pz;
            xx[r] = fmaf(px, px, fmaf(py, py, pz * pz));
        }
        acc2[p] = float2v{3.4e38f, 3.4e38f};
    }

    __syncthreads();

    // Manual register double-buffer of the 2-j LDS reads.
    float4 qa = qs[0];
    float4 qb = qs[1];
    #pragma unroll 4
    for (int j = 0; j < CHUNK; j += 2) {
        // Prefetch next pair (wraps harmlessly on the last iteration).
        float4 qa_n = qs[(j + 2) & (CHUNK - 1)];
        float4 qb_n = qs[(j + 3) & (CHUNK - 1)];

        float2v xy0 = {qa.x, qa.y}, zw0 = {qa.z, qa.w};
        float2v xy1 = {qb.x, qb.y}, zw1 = {qb.z, qb.w};
        #pragma unroll
        for (int p = 0; p < RP; p++) {
            float2v g0, g1;
            // g = q.z * mz + q.w   (q.z, q.w broadcast to both halves)
            asm("v_pk_fma_f32 %0, %1, %2, %1 op_sel:[0,0,1] op_sel_hi:[0,1,1]"
                : "=v"(g0) : "v"(zw0), "v"(mz2[p]));
            asm("v_pk_fma_f32 %0, %1, %2, %1 op_sel:[0,0,1] op_sel_hi:[0,1,1]"
                : "=v"(g1) : "v"(zw1), "v"(mz2[p]));
            // g = q.y * my + g     (q.y = hi half, broadcast)
            asm("v_pk_fma_f32 %0, %1, %2, %3 op_sel:[1,0,0] op_sel_hi:[1,1,1]"
                : "=v"(g0) : "v"(xy0), "v"(my2[p]), "v"(g0));
            asm("v_pk_fma_f32 %0, %1, %2, %3 op_sel:[1,0,0] op_sel_hi:[1,1,1]"
                : "=v"(g1) : "v"(xy1), "v"(my2[p]), "v"(g1));
            // g = q.x * mx + g     (q.x = lo half, broadcast)
            asm("v_pk_fma_f32 %0, %1, %2, %3 op_sel:[0,0,0] op_sel_hi:[0,1,1]"
                : "=v"(g0) : "v"(xy0), "v"(mx2[p]), "v"(g0));
            asm("v_pk_fma_f32 %0, %1, %2, %3 op_sel:[0,0,0] op_sel_hi:[0,1,1]"
                : "=v"(g1) : "v"(xy1), "v"(mx2[p]), "v"(g1));
            // 2-j fold -> v_min3_f32 per half.
            acc2[p].x = fminf(fminf(acc2[p].x, g0.x), g1.x);
            acc2[p].y = fminf(fminf(acc2[p].y, g0.y), g1.y);
        }
        qa = qa_n;
        qb = qb_n;
    }

    // Coalesced partial stores (kernel-boundary coherence; no atomics).
    float* dst = partials + (size_t)chunk * TOT + (size_t)dir * PTS + (size_t)b * N;
    #pragma unroll
    for (int p = 0; p < RP; p++) {
        dst[threadIdx.x + (2 * p) * TPB]     = fmaxf(acc2[p].x + xx[2 * p], 0.0f);
        dst[threadIdx.x + (2 * p + 1) * TPB] = fmaxf(acc2[p].y + xx[2 * p + 1], 0.0f);
    }
}

// Phase 2: per point min over KC partial rows; sqrt; block-sum; one
// atomicAdd per block into the main-zeroed scalar output.
__global__ __launch_bounds__(256) void chamfer_finish(
        const float* __restrict__ partials, float* __restrict__ out, float scale) {
    int p = blockIdx.x * 256 + threadIdx.x;   // [0, TOT)
    float m = partials[p];
    #pragma unroll
    for (int c = 1; c < KC; c++) m = fminf(m, partials[(size_t)c * TOT + p]);
    float s = sqrtf(1e-8f + m) * scale;

    #pragma unroll
    for (int off = 32; off > 0; off >>= 1) s += __shfl_down(s, off, 64);

    __shared__ float part[4];
    const int wid = threadIdx.x >> 6, lane = threadIdx.x & 63;
    if (lane == 0) part[wid] = s;
    __syncthreads();
    if (threadIdx.x == 0) {
        atomicAdd(out, part[0] + part[1] + part[2] + part[3]);
    }
}

extern "C" void kernel_launch(void* const* d_in, const int* in_sizes, int n_in,
                              void* d_out, int out_size, void* d_ws, size_t ws_size,
                              hipStream_t stream) {
    const float* x1 = (const float*)d_in[0];   // (B, N, 3)
    const float* y1 = (const float*)d_in[1];   // (B, N, 3)
    float* out = (float*)d_out;

    float* partials = (float*)d_ws;            // KC * TOT floats = 16 MB

    dim3 grid(KC, 2, B);                       // 64 x 2 x 8 = 1024 blocks
    chamfer_main<<<grid, TPB, 0, stream>>>(x1, y1, partials, out);

    chamfer_finish<<<TOT / 256, 256, 0, stream>>>(partials, out, 1.0f / (B * N));
}